// Round 1
// baseline (116.618 us; speedup 1.0000x reference)
//
#include <hip/hip_runtime.h>
#include <math.h>

namespace {

constexpr int DD = 1024;        // d
constexpr int NC = 3 * DD;      // columns of x
constexpr int NROWS = 8192;     // B*T = 4*2048
constexpr int CH1 = 32;         // row chunks for col stats
constexpr int CH2 = 128;        // row chunks for main pass
constexpr int CH3 = 256;        // row chunks for final pass
constexpr float GAMMA = 5.0f;
constexpr float EPS_NORM = 1e-5f;
constexpr float EPS_W = 1e-8f;

// ---------------- pass 1: per-column sum / sumsq of x ----------------
__global__ void col_stats_kernel(const float* __restrict__ x,
                                 float* __restrict__ psum,
                                 float* __restrict__ psq) {
  int col = blockIdx.x * blockDim.x + threadIdx.x;   // 0..3071
  int chunk = blockIdx.y;                            // 0..CH1-1
  const int rows_per = NROWS / CH1;
  int r0 = chunk * rows_per;
  float s = 0.f, q = 0.f;
  for (int r = r0; r < r0 + rows_per; ++r) {
    float v = x[(size_t)r * NC + col];
    s += v;
    q += v * v;
  }
  psum[chunk * NC + col] = s;
  psq[chunk * NC + col] = q;
}

// ---------------- pass 2: per-(p,d) coefficients ----------------
// Householder QR (LAPACK sgeqrf/sorgqr sign convention) of each 3x3 a[d],
// then fold softplus(w), column stats, g into: norm_h_j = (xi-m)*A_j + beta_j
__global__ void coef_kernel(const float* __restrict__ psum, const float* __restrict__ psq,
                            const float* __restrict__ wq, const float* __restrict__ aq,
                            const float* __restrict__ gq, const float* __restrict__ betaq,
                            const float* __restrict__ wk, const float* __restrict__ ak,
                            const float* __restrict__ gk, const float* __restrict__ betak,
                            const float* __restrict__ wv, const float* __restrict__ av,
                            const float* __restrict__ gv, const float* __restrict__ betav,
                            float* __restrict__ m_arr,   // [NC]
                            float* __restrict__ A_arr,   // [3][NC]
                            float* __restrict__ B_arr) { // [3][NC]
  int c = blockIdx.x * blockDim.x + threadIdx.x;
  if (c >= NC) return;
  int p = c / DD;
  int d = c - p * DD;
  const float* w; const float* a; const float* g; const float* beta;
  if (p == 0)      { w = wq; a = aq; g = gq; beta = betaq; }
  else if (p == 1) { w = wk; a = ak; g = gk; beta = betak; }
  else             { w = wv; a = av; g = gv; beta = betav; }

  // reduce column stats (fixed order -> deterministic)
  double s = 0.0, q = 0.0;
  for (int ch = 0; ch < CH1; ++ch) { s += psum[ch * NC + c]; q += psq[ch * NC + c]; }
  float mean = (float)(s / NROWS);
  float var  = (float)(q / NROWS - (s / NROWS) * (s / NROWS));
  if (var < 0.f) var = 0.f;

  // load 3x3
  float A[3][3];
  #pragma unroll
  for (int i = 0; i < 3; ++i)
    #pragma unroll
    for (int j = 0; j < 3; ++j) A[i][j] = a[((size_t)d * 3 + i) * 3 + j];

  // Householder QR, LAPACK convention: beta = -sign(alpha)*||col||
  float v1y = 0.f, v1z = 0.f, v2z = 0.f;
  float t1 = 0.f, t2 = 0.f;
  {
    float alpha = A[0][0];
    float xn2 = A[1][0] * A[1][0] + A[2][0] * A[2][0];
    if (xn2 > 0.f) {
      float beta_ = -copysignf(sqrtf(alpha * alpha + xn2), alpha);
      t1 = (beta_ - alpha) / beta_;
      float inv = 1.0f / (alpha - beta_);
      v1y = A[1][0] * inv; v1z = A[2][0] * inv;
      #pragma unroll
      for (int j = 1; j < 3; ++j) {  // apply H1 to cols 1,2
        float dot = A[0][j] + A[1][j] * v1y + A[2][j] * v1z;
        float f = t1 * dot;
        A[0][j] -= f; A[1][j] -= f * v1y; A[2][j] -= f * v1z;
      }
    }
  }
  {
    float alpha = A[1][1];
    float x2 = A[2][1];
    if (x2 != 0.f) {
      float beta_ = -copysignf(sqrtf(alpha * alpha + x2 * x2), alpha);
      t2 = (beta_ - alpha) / beta_;
      v2z = x2 / (alpha - beta_);
    }
  }
  // Q = (I - t1 v1 v1^T)(I - t2 v2 v2^T), v1=[1,v1y,v1z], v2=[0,1,v2z]
  float v1[3] = {1.f, v1y, v1z};
  float v2[3] = {0.f, 1.f, v2z};
  float v12 = v1y + v1z * v2z;
  float Q[3][3];
  #pragma unroll
  for (int i = 0; i < 3; ++i)
    #pragma unroll
    for (int j = 0; j < 3; ++j) {
      float e = (i == j) ? 1.f : 0.f;
      Q[i][j] = e - t1 * v1[i] * v1[j] - t2 * v2[i] * v2[j]
                  + t1 * t2 * v12 * v1[i] * v2[j];
    }

  // softplus weights; bias b cancels under batch norm.
  float sp0 = log1pf(expf(w[d * 3 + 0]));
  float sp1 = log1pf(expf(w[d * 3 + 1]));
  float sp2 = log1pf(expf(w[d * 3 + 2]));
  #pragma unroll
  for (int j = 0; j < 3; ++j) {
    float W = sp0 * Q[0][j] + sp1 * Q[1][j] + sp2 * Q[2][j];
    float scale = W * g[d * 3 + j] / sqrtf(W * W * var + EPS_NORM);
    A_arr[j * NC + c] = scale;
    B_arr[j * NC + c] = beta[d * 3 + j];
  }
  m_arr[c] = mean;
}

// ---------------- shared elementwise math ----------------
struct Coefs {
  float mq, mk, mv;
  float Aq[3], Bq[3], Ak[3], Bk[3], Av[3], Bv[3];
};

__device__ __forceinline__ Coefs load_coefs(int d,
                                            const float* __restrict__ m_arr,
                                            const float* __restrict__ A_arr,
                                            const float* __restrict__ B_arr) {
  Coefs C;
  C.mq = m_arr[d]; C.mk = m_arr[DD + d]; C.mv = m_arr[2 * DD + d];
  #pragma unroll
  for (int j = 0; j < 3; ++j) {
    C.Aq[j] = A_arr[j * NC + d];
    C.Ak[j] = A_arr[j * NC + DD + d];
    C.Av[j] = A_arr[j * NC + 2 * DD + d];
    C.Bq[j] = B_arr[j * NC + d];
    C.Bk[j] = B_arr[j * NC + DD + d];
    C.Bv[j] = B_arr[j * NC + 2 * DD + d];
  }
  return C;
}

__device__ __forceinline__ float convex_out(float xq, float xk, float xv,
                                            const Coefs& C) {
  float dq = xq - C.mq, dk = xk - C.mk, dv = xv - C.mv;
  float num = 0.f, den = EPS_W;
  #pragma unroll
  for (int j = 0; j < 3; ++j) {
    float Qj = fmaf(dq, C.Aq[j], C.Bq[j]);
    float Kj = fmaf(dk, C.Ak[j], C.Bk[j]);
    float Vj = fmaf(dv, C.Av[j], C.Bv[j]);
    float sc = 1.f / (1.f + expf(-GAMMA * Qj * Kj));
    num = fmaf(sc, Vj, num);
    den += sc;
  }
  return num / den;
}

// ---------------- pass 3: out value + per-d partial stats ----------------
__global__ void main_pass_kernel(const float* __restrict__ x,
                                 const float* __restrict__ m_arr,
                                 const float* __restrict__ A_arr,
                                 const float* __restrict__ B_arr,
                                 float* __restrict__ opsum,
                                 float* __restrict__ opsq) {
  int d = blockIdx.x * blockDim.x + threadIdx.x;  // 0..1023
  int chunk = blockIdx.y;                         // 0..CH2-1
  Coefs C = load_coefs(d, m_arr, A_arr, B_arr);
  const int rows_per = NROWS / CH2;
  int r0 = chunk * rows_per;
  float s = 0.f, q = 0.f;
  for (int r = r0; r < r0 + rows_per; ++r) {
    const float* row = x + (size_t)r * NC;
    float o = convex_out(row[d], row[DD + d], row[2 * DD + d], C);
    s += o;
    q += o * o;
  }
  opsum[chunk * DD + d] = s;
  opsq[chunk * DD + d] = q;
}

// ---------------- pass 4: final per-d mean / scale ----------------
__global__ void out_stats_kernel(const float* __restrict__ opsum,
                                 const float* __restrict__ opsq,
                                 const float* __restrict__ g_out,
                                 const float* __restrict__ b_out,
                                 float* __restrict__ om,
                                 float* __restrict__ osc,
                                 float* __restrict__ ob) {
  int d = blockIdx.x * blockDim.x + threadIdx.x;
  if (d >= DD) return;
  double s = 0.0, q = 0.0;
  for (int ch = 0; ch < CH2; ++ch) { s += opsum[ch * DD + d]; q += opsq[ch * DD + d]; }
  float mean = (float)(s / NROWS);
  float var  = (float)(q / NROWS - (s / NROWS) * (s / NROWS));
  if (var < 0.f) var = 0.f;
  om[d] = mean;
  osc[d] = g_out[d] / sqrtf(var + EPS_NORM);
  ob[d] = b_out[d];
}

// ---------------- pass 5: recompute + final norm + write ----------------
__global__ void final_pass_kernel(const float* __restrict__ x,
                                  const float* __restrict__ m_arr,
                                  const float* __restrict__ A_arr,
                                  const float* __restrict__ B_arr,
                                  const float* __restrict__ om,
                                  const float* __restrict__ osc,
                                  const float* __restrict__ ob,
                                  float* __restrict__ out) {
  int d = blockIdx.x * blockDim.x + threadIdx.x;
  int chunk = blockIdx.y;  // 0..CH3-1
  Coefs C = load_coefs(d, m_arr, A_arr, B_arr);
  float md = om[d], sd = osc[d], bd = ob[d];
  const int rows_per = NROWS / CH3;
  int r0 = chunk * rows_per;
  for (int r = r0; r < r0 + rows_per; ++r) {
    const float* row = x + (size_t)r * NC;
    float o = convex_out(row[d], row[DD + d], row[2 * DD + d], C);
    out[(size_t)r * DD + d] = (o - md) * sd + bd;
  }
}

}  // namespace

extern "C" void kernel_launch(void* const* d_in, const int* in_sizes, int n_in,
                              void* d_out, int out_size, void* d_ws, size_t ws_size,
                              hipStream_t stream) {
  const float* x     = (const float*)d_in[0];
  const float* wq    = (const float*)d_in[1];
  const float* aq    = (const float*)d_in[3];
  const float* gq    = (const float*)d_in[4];
  const float* betaq = (const float*)d_in[5];
  const float* wk    = (const float*)d_in[6];
  const float* ak    = (const float*)d_in[8];
  const float* gk    = (const float*)d_in[9];
  const float* betak = (const float*)d_in[10];
  const float* wv    = (const float*)d_in[11];
  const float* av    = (const float*)d_in[13];
  const float* gv    = (const float*)d_in[14];
  const float* betav = (const float*)d_in[15];
  const float* g_out = (const float*)d_in[16];
  const float* b_out = (const float*)d_in[17];
  float* out = (float*)d_out;

  // workspace carve (floats)
  float* ws = (float*)d_ws;
  float* psum  = ws;                    // CH1*NC
  float* psq   = psum + CH1 * NC;       // CH1*NC
  float* m_arr = psq + CH1 * NC;        // NC
  float* A_arr = m_arr + NC;            // 3*NC
  float* B_arr = A_arr + 3 * NC;        // 3*NC
  float* opsum = B_arr + 3 * NC;        // CH2*DD
  float* opsq  = opsum + CH2 * DD;      // CH2*DD
  float* om    = opsq + CH2 * DD;       // DD
  float* osc   = om + DD;               // DD
  float* ob    = osc + DD;              // DD

  dim3 blk(256);

  col_stats_kernel<<<dim3(NC / 256, CH1), blk, 0, stream>>>(x, psum, psq);

  coef_kernel<<<dim3((NC + 255) / 256), blk, 0, stream>>>(
      psum, psq, wq, aq, gq, betaq, wk, ak, gk, betak, wv, av, gv, betav,
      m_arr, A_arr, B_arr);

  main_pass_kernel<<<dim3(DD / 256, CH2), blk, 0, stream>>>(
      x, m_arr, A_arr, B_arr, opsum, opsq);

  out_stats_kernel<<<dim3((DD + 255) / 256), blk, 0, stream>>>(
      opsum, opsq, g_out, b_out, om, osc, ob);

  final_pass_kernel<<<dim3(DD / 256, CH3), blk, 0, stream>>>(
      x, m_arr, A_arr, B_arr, om, osc, ob, out);
}

// Round 2
// 88.495 us; speedup vs baseline: 1.3178x; 1.3178x over previous
//
#include <hip/hip_runtime.h>
#include <math.h>

namespace {

constexpr int DD = 1024;        // d
constexpr int NC = 3 * DD;      // columns of x (3072)
constexpr int NG = NC / 4;      // float4 groups per row (768)
constexpr int DG = DD / 4;      // float4 groups per output row (256)
constexpr int NROWS = 8192;     // B*T
constexpr float GAMMA = 5.0f;
constexpr float EPS_NORM = 1e-5f;
constexpr float EPS_W = 1e-8f;

// ================= pass 1: per-column sum/sumsq (float4) =================
// grid (NG/256=3, CH), block 256
template <int CH>
__global__ void col_stats_kernel(const float* __restrict__ x,
                                 float4* __restrict__ psum,
                                 float4* __restrict__ psq) {
  int cg = blockIdx.x * 256 + threadIdx.x;   // 0..767
  int chunk = blockIdx.y;
  constexpr int rows_per = NROWS / CH;
  const float4* __restrict__ x4 = (const float4*)x;
  size_t base = (size_t)(chunk * rows_per) * NG + cg;
  float4 s = {0.f, 0.f, 0.f, 0.f};
  float4 q = {0.f, 0.f, 0.f, 0.f};
  #pragma unroll 8
  for (int r = 0; r < rows_per; ++r) {
    float4 v = x4[base + (size_t)r * NG];
    s.x += v.x; s.y += v.y; s.z += v.z; s.w += v.w;
    q.x += v.x * v.x; q.y += v.y * v.y; q.z += v.z * v.z; q.w += v.w * v.w;
  }
  psum[chunk * NG + cg] = s;
  psq[chunk * NG + cg] = q;
}

// ================= pass 2: reduce stats + QR -> coefficients =================
// grid NC blocks, 64 threads; lane-reduce over CH chunks, lane 0 does QR.
template <int CH>
__global__ void coef_kernel(const float* __restrict__ psum, const float* __restrict__ psq,
                            const float* __restrict__ wq, const float* __restrict__ aq,
                            const float* __restrict__ gq, const float* __restrict__ betaq,
                            const float* __restrict__ wk, const float* __restrict__ ak,
                            const float* __restrict__ gk, const float* __restrict__ betak,
                            const float* __restrict__ wv, const float* __restrict__ av,
                            const float* __restrict__ gv, const float* __restrict__ betav,
                            float* __restrict__ m_arr,   // [NC]
                            float* __restrict__ A_arr,   // [3][NC]
                            float* __restrict__ B_arr) { // [3][NC]
  int c = blockIdx.x;
  int lane = threadIdx.x;
  float s = 0.f, q = 0.f;
  for (int ch = lane; ch < CH; ch += 64) {
    s += psum[(size_t)ch * NC + c];
    q += psq[(size_t)ch * NC + c];
  }
  #pragma unroll
  for (int off = 32; off > 0; off >>= 1) {
    s += __shfl_down(s, off);
    q += __shfl_down(q, off);
  }
  if (lane != 0) return;

  float mean = s / NROWS;
  float var = q / NROWS - mean * mean;
  if (var < 0.f) var = 0.f;

  int p = c / DD;
  int d = c - p * DD;
  const float* w; const float* a; const float* g; const float* beta;
  if (p == 0)      { w = wq; a = aq; g = gq; beta = betaq; }
  else if (p == 1) { w = wk; a = ak; g = gk; beta = betak; }
  else             { w = wv; a = av; g = gv; beta = betav; }

  float A[3][3];
  #pragma unroll
  for (int i = 0; i < 3; ++i)
    #pragma unroll
    for (int j = 0; j < 3; ++j) A[i][j] = a[((size_t)d * 3 + i) * 3 + j];

  // Householder QR, LAPACK sign convention
  float v1y = 0.f, v1z = 0.f, v2z = 0.f, t1 = 0.f, t2 = 0.f;
  {
    float alpha = A[0][0];
    float xn2 = A[1][0] * A[1][0] + A[2][0] * A[2][0];
    if (xn2 > 0.f) {
      float beta_ = -copysignf(sqrtf(alpha * alpha + xn2), alpha);
      t1 = (beta_ - alpha) / beta_;
      float inv = 1.0f / (alpha - beta_);
      v1y = A[1][0] * inv; v1z = A[2][0] * inv;
      #pragma unroll
      for (int j = 1; j < 3; ++j) {
        float dot = A[0][j] + A[1][j] * v1y + A[2][j] * v1z;
        float f = t1 * dot;
        A[0][j] -= f; A[1][j] -= f * v1y; A[2][j] -= f * v1z;
      }
    }
  }
  {
    float alpha = A[1][1];
    float x2 = A[2][1];
    if (x2 != 0.f) {
      float beta_ = -copysignf(sqrtf(alpha * alpha + x2 * x2), alpha);
      t2 = (beta_ - alpha) / beta_;
      v2z = x2 / (alpha - beta_);
    }
  }
  float v1[3] = {1.f, v1y, v1z};
  float v2[3] = {0.f, 1.f, v2z};
  float v12 = v1y + v1z * v2z;

  float sp0 = log1pf(expf(w[d * 3 + 0]));
  float sp1 = log1pf(expf(w[d * 3 + 1]));
  float sp2 = log1pf(expf(w[d * 3 + 2]));

  #pragma unroll
  for (int j = 0; j < 3; ++j) {
    float Q0 = (0 == j ? 1.f : 0.f) - t1 * v1[0] * v1[j] - t2 * v2[0] * v2[j]
               + t1 * t2 * v12 * v1[0] * v2[j];
    float Q1 = (1 == j ? 1.f : 0.f) - t1 * v1[1] * v1[j] - t2 * v2[1] * v2[j]
               + t1 * t2 * v12 * v1[1] * v2[j];
    float Q2 = (2 == j ? 1.f : 0.f) - t1 * v1[2] * v1[j] - t2 * v2[2] * v2[j]
               + t1 * t2 * v12 * v1[2] * v2[j];
    float W = sp0 * Q0 + sp1 * Q1 + sp2 * Q2;
    float scale = W * g[d * 3 + j] / sqrtf(W * W * var + EPS_NORM);
    A_arr[j * NC + c] = scale;
    B_arr[j * NC + c] = beta[d * 3 + j];
  }
  m_arr[c] = mean;
}

// ================= shared elementwise math (4-wide) =================
struct Coefs4 {
  float4 mq, mk, mv;
  float4 Aq[3], Bq[3], Ak[3], Bk[3], Av[3], Bv[3];
};

__device__ __forceinline__ Coefs4 load_coefs4(int t,
                                              const float* __restrict__ m_arr,
                                              const float* __restrict__ A_arr,
                                              const float* __restrict__ B_arr) {
  Coefs4 C;
  C.mq = ((const float4*)m_arr)[t];
  C.mk = ((const float4*)(m_arr + DD))[t];
  C.mv = ((const float4*)(m_arr + 2 * DD))[t];
  #pragma unroll
  for (int j = 0; j < 3; ++j) {
    C.Aq[j] = ((const float4*)(A_arr + j * NC))[t];
    C.Ak[j] = ((const float4*)(A_arr + j * NC + DD))[t];
    C.Av[j] = ((const float4*)(A_arr + j * NC + 2 * DD))[t];
    C.Bq[j] = ((const float4*)(B_arr + j * NC))[t];
    C.Bk[j] = ((const float4*)(B_arr + j * NC + DD))[t];
    C.Bv[j] = ((const float4*)(B_arr + j * NC + 2 * DD))[t];
  }
  return C;
}

__device__ __forceinline__ float conv1(float xq, float xk, float xv,
                                       float mq, float mk, float mv,
                                       const float* Aq, const float* Bq,
                                       const float* Ak, const float* Bk,
                                       const float* Av, const float* Bv) {
  float dq = xq - mq, dk = xk - mk, dv = xv - mv;
  float num = 0.f, den = EPS_W;
  #pragma unroll
  for (int j = 0; j < 3; ++j) {
    float Qj = fmaf(dq, Aq[j], Bq[j]);
    float Kj = fmaf(dk, Ak[j], Bk[j]);
    float Vj = fmaf(dv, Av[j], Bv[j]);
    float sc = 1.f / (1.f + __expf(-GAMMA * Qj * Kj));
    num = fmaf(sc, Vj, num);
    den += sc;
  }
  return num / den;
}

#define CONV4(o, xq, xk, xv, C)                                                  \
  {                                                                              \
    float aq_[3], bq_[3], ak_[3], bk_[3], av_[3], bv_[3];                        \
    _Pragma("unroll") for (int j = 0; j < 3; ++j) {                              \
      aq_[j] = ((const float*)&C.Aq[j])[kk]; bq_[j] = ((const float*)&C.Bq[j])[kk]; \
      ak_[j] = ((const float*)&C.Ak[j])[kk]; bk_[j] = ((const float*)&C.Bk[j])[kk]; \
      av_[j] = ((const float*)&C.Av[j])[kk]; bv_[j] = ((const float*)&C.Bv[j])[kk]; \
    }                                                                            \
    ((float*)&o)[kk] = conv1(((const float*)&xq)[kk], ((const float*)&xk)[kk],   \
                             ((const float*)&xv)[kk], ((const float*)&C.mq)[kk], \
                             ((const float*)&C.mk)[kk], ((const float*)&C.mv)[kk], \
                             aq_, bq_, ak_, bk_, av_, bv_);                      \
  }

__device__ __forceinline__ float4 conv4(float4 xq, float4 xk, float4 xv,
                                        const Coefs4& C) {
  float4 o;
  #pragma unroll
  for (int kk = 0; kk < 4; ++kk) CONV4(o, xq, xk, xv, C);
  return o;
}

// ================= pass 3: compute o (+optional store) + partial stats =====
// grid CH blocks, 256 threads; thread t owns d-group t.
template <int CH, bool WRITE_O>
__global__ void main_pass_kernel(const float* __restrict__ x,
                                 const float* __restrict__ m_arr,
                                 const float* __restrict__ A_arr,
                                 const float* __restrict__ B_arr,
                                 float4* __restrict__ o_arr,
                                 float4* __restrict__ opsum,
                                 float4* __restrict__ opsq) {
  int t = threadIdx.x;             // 0..255
  int chunk = blockIdx.x;          // 0..CH-1
  constexpr int rows_per = NROWS / CH;
  Coefs4 C = load_coefs4(t, m_arr, A_arr, B_arr);
  float4 s = {0.f, 0.f, 0.f, 0.f};
  float4 q = {0.f, 0.f, 0.f, 0.f};
  int r0 = chunk * rows_per;
  for (int r = r0; r < r0 + rows_per; ++r) {
    const float4* __restrict__ row = (const float4*)(x + (size_t)r * NC);
    float4 xq = row[t], xk = row[DG + t], xv = row[2 * DG + t];
    float4 o = conv4(xq, xk, xv, C);
    s.x += o.x; s.y += o.y; s.z += o.z; s.w += o.w;
    q.x += o.x * o.x; q.y += o.y * o.y; q.z += o.z * o.z; q.w += o.w * o.w;
    if (WRITE_O) o_arr[(size_t)r * DG + t] = o;
  }
  opsum[chunk * DG + t] = s;
  opsq[chunk * DG + t] = q;
}

// ================= pass 4: out stats =================
// grid DD blocks, 64 threads
template <int CH>
__global__ void out_stats_kernel(const float* __restrict__ opsum,
                                 const float* __restrict__ opsq,
                                 const float* __restrict__ g_out,
                                 const float* __restrict__ b_out,
                                 float* __restrict__ om,
                                 float* __restrict__ osc,
                                 float* __restrict__ ob) {
  int d = blockIdx.x;
  int lane = threadIdx.x;
  float s = 0.f, q = 0.f;
  for (int ch = lane; ch < CH; ch += 64) {
    s += opsum[(size_t)ch * DD + d];
    q += opsq[(size_t)ch * DD + d];
  }
  #pragma unroll
  for (int off = 32; off > 0; off >>= 1) {
    s += __shfl_down(s, off);
    q += __shfl_down(q, off);
  }
  if (lane != 0) return;
  float mean = s / NROWS;
  float var = q / NROWS - mean * mean;
  if (var < 0.f) var = 0.f;
  om[d] = mean;
  osc[d] = g_out[d] / sqrtf(var + EPS_NORM);
  ob[d] = b_out[d];
}

// ================= pass 5a: final from stored o =================
// grid NROWS/4 blocks, 256 threads (4 rows per block)
__global__ void final_from_o_kernel(const float4* __restrict__ o_arr,
                                    const float* __restrict__ om,
                                    const float* __restrict__ osc,
                                    const float* __restrict__ ob,
                                    float4* __restrict__ out) {
  int t = threadIdx.x;
  int r0 = blockIdx.x * 4;
  float4 m = ((const float4*)om)[t];
  float4 sc = ((const float4*)osc)[t];
  float4 b = ((const float4*)ob)[t];
  #pragma unroll
  for (int rr = 0; rr < 4; ++rr) {
    size_t idx = (size_t)(r0 + rr) * DG + t;
    float4 o = o_arr[idx];
    float4 y;
    y.x = (o.x - m.x) * sc.x + b.x;
    y.y = (o.y - m.y) * sc.y + b.y;
    y.z = (o.z - m.z) * sc.z + b.z;
    y.w = (o.w - m.w) * sc.w + b.w;
    out[idx] = y;
  }
}

// ================= pass 5b: final with recompute (small-ws fallback) =====
template <int CH>
__global__ void final_recompute_kernel(const float* __restrict__ x,
                                       const float* __restrict__ m_arr,
                                       const float* __restrict__ A_arr,
                                       const float* __restrict__ B_arr,
                                       const float* __restrict__ om,
                                       const float* __restrict__ osc,
                                       const float* __restrict__ ob,
                                       float4* __restrict__ out) {
  int t = threadIdx.x;
  int chunk = blockIdx.x;
  constexpr int rows_per = NROWS / CH;
  Coefs4 C = load_coefs4(t, m_arr, A_arr, B_arr);
  float4 m = ((const float4*)om)[t];
  float4 sc = ((const float4*)osc)[t];
  float4 b = ((const float4*)ob)[t];
  int r0 = chunk * rows_per;
  for (int r = r0; r < r0 + rows_per; ++r) {
    const float4* __restrict__ row = (const float4*)(x + (size_t)r * NC);
    float4 xq = row[t], xk = row[DG + t], xv = row[2 * DG + t];
    float4 o = conv4(xq, xk, xv, C);
    float4 y;
    y.x = (o.x - m.x) * sc.x + b.x;
    y.y = (o.y - m.y) * sc.y + b.y;
    y.z = (o.z - m.z) * sc.z + b.z;
    y.w = (o.w - m.w) * sc.w + b.w;
    out[(size_t)r * DG + t] = y;
  }
}

}  // namespace

extern "C" void kernel_launch(void* const* d_in, const int* in_sizes, int n_in,
                              void* d_out, int out_size, void* d_ws, size_t ws_size,
                              hipStream_t stream) {
  const float* x     = (const float*)d_in[0];
  const float* wq    = (const float*)d_in[1];
  const float* aq    = (const float*)d_in[3];
  const float* gq    = (const float*)d_in[4];
  const float* betaq = (const float*)d_in[5];
  const float* wk    = (const float*)d_in[6];
  const float* ak    = (const float*)d_in[8];
  const float* gk    = (const float*)d_in[9];
  const float* betak = (const float*)d_in[10];
  const float* wv    = (const float*)d_in[11];
  const float* av    = (const float*)d_in[13];
  const float* gv    = (const float*)d_in[14];
  const float* betav = (const float*)d_in[15];
  const float* g_out = (const float*)d_in[16];
  const float* b_out = (const float*)d_in[17];
  float4* out = (float4*)d_out;

  char* ws = (char*)d_ws;
  auto carve = [&](size_t bytes) { char* p = ws; ws += bytes; return p; };

  // ---- tier selection by ws_size ----
  constexpr size_t fB = sizeof(float);
  // big tier: CH1=256, CH2=512, store o
  constexpr size_t bigNeed =
      2 * (256 * (size_t)NC * fB) + 7 * NC * fB +
      2 * (512 * (size_t)DD * fB) + 3 * DD * fB +
      (size_t)NROWS * DD * fB + 1024;
  // mid tier: CH1=256, CH2=512, recompute
  constexpr size_t midNeed =
      2 * (256 * (size_t)NC * fB) + 7 * NC * fB +
      2 * (512 * (size_t)DD * fB) + 3 * DD * fB + 1024;

  if (ws_size >= bigNeed) {
    constexpr int CH1 = 256, CH2 = 512;
    float4* psum = (float4*)carve(CH1 * (size_t)NC * fB);
    float4* psq  = (float4*)carve(CH1 * (size_t)NC * fB);
    float* m_arr = (float*)carve(NC * fB);
    float* A_arr = (float*)carve(3 * NC * fB);
    float* B_arr = (float*)carve(3 * NC * fB);
    float4* opsum = (float4*)carve(CH2 * (size_t)DD * fB);
    float4* opsq  = (float4*)carve(CH2 * (size_t)DD * fB);
    float* om  = (float*)carve(DD * fB);
    float* osc = (float*)carve(DD * fB);
    float* ob  = (float*)carve(DD * fB);
    float4* o_arr = (float4*)carve((size_t)NROWS * DD * fB);

    col_stats_kernel<CH1><<<dim3(NG / 256, CH1), dim3(256), 0, stream>>>(x, psum, psq);
    coef_kernel<CH1><<<dim3(NC), dim3(64), 0, stream>>>(
        (const float*)psum, (const float*)psq, wq, aq, gq, betaq, wk, ak, gk, betak,
        wv, av, gv, betav, m_arr, A_arr, B_arr);
    main_pass_kernel<CH2, true><<<dim3(CH2), dim3(256), 0, stream>>>(
        x, m_arr, A_arr, B_arr, o_arr, opsum, opsq);
    out_stats_kernel<CH2><<<dim3(DD), dim3(64), 0, stream>>>(
        (const float*)opsum, (const float*)opsq, g_out, b_out, om, osc, ob);
    final_from_o_kernel<<<dim3(NROWS / 4), dim3(256), 0, stream>>>(
        o_arr, om, osc, ob, out);
  } else if (ws_size >= midNeed) {
    constexpr int CH1 = 256, CH2 = 512;
    float4* psum = (float4*)carve(CH1 * (size_t)NC * fB);
    float4* psq  = (float4*)carve(CH1 * (size_t)NC * fB);
    float* m_arr = (float*)carve(NC * fB);
    float* A_arr = (float*)carve(3 * NC * fB);
    float* B_arr = (float*)carve(3 * NC * fB);
    float4* opsum = (float4*)carve(CH2 * (size_t)DD * fB);
    float4* opsq  = (float4*)carve(CH2 * (size_t)DD * fB);
    float* om  = (float*)carve(DD * fB);
    float* osc = (float*)carve(DD * fB);
    float* ob  = (float*)carve(DD * fB);

    col_stats_kernel<CH1><<<dim3(NG / 256, CH1), dim3(256), 0, stream>>>(x, psum, psq);
    coef_kernel<CH1><<<dim3(NC), dim3(64), 0, stream>>>(
        (const float*)psum, (const float*)psq, wq, aq, gq, betaq, wk, ak, gk, betak,
        wv, av, gv, betav, m_arr, A_arr, B_arr);
    main_pass_kernel<CH2, false><<<dim3(CH2), dim3(256), 0, stream>>>(
        x, m_arr, A_arr, B_arr, nullptr, opsum, opsq);
    out_stats_kernel<CH2><<<dim3(DD), dim3(64), 0, stream>>>(
        (const float*)opsum, (const float*)opsq, g_out, b_out, om, osc, ob);
    final_recompute_kernel<512><<<dim3(512), dim3(256), 0, stream>>>(
        x, m_arr, A_arr, B_arr, om, osc, ob, out);
  } else {
    // minimal tier: CH1=32, CH2=128 (~1.9 MB, matches round-1 footprint)
    constexpr int CH1 = 32, CH2 = 128;
    float4* psum = (float4*)carve(CH1 * (size_t)NC * fB);
    float4* psq  = (float4*)carve(CH1 * (size_t)NC * fB);
    float* m_arr = (float*)carve(NC * fB);
    float* A_arr = (float*)carve(3 * NC * fB);
    float* B_arr = (float*)carve(3 * NC * fB);
    float4* opsum = (float4*)carve(CH2 * (size_t)DD * fB);
    float4* opsq  = (float4*)carve(CH2 * (size_t)DD * fB);
    float* om  = (float*)carve(DD * fB);
    float* osc = (float*)carve(DD * fB);
    float* ob  = (float*)carve(DD * fB);

    col_stats_kernel<CH1><<<dim3(NG / 256, CH1), dim3(256), 0, stream>>>(x, psum, psq);
    coef_kernel<CH1><<<dim3(NC), dim3(64), 0, stream>>>(
        (const float*)psum, (const float*)psq, wq, aq, gq, betaq, wk, ak, gk, betak,
        wv, av, gv, betav, m_arr, A_arr, B_arr);
    main_pass_kernel<CH2, false><<<dim3(CH2), dim3(256), 0, stream>>>(
        x, m_arr, A_arr, B_arr, nullptr, opsum, opsq);
    out_stats_kernel<CH2><<<dim3(DD), dim3(64), 0, stream>>>(
        (const float*)opsum, (const float*)opsq, g_out, b_out, om, osc, ob);
    final_recompute_kernel<128><<<dim3(128), dim3(256), 0, stream>>>(
        x, m_arr, A_arr, B_arr, om, osc, ob, out);
  }
}